// Round 8
// baseline (188.649 us; speedup 1.0000x reference)
//
#include <hip/hip_runtime.h>
#include <math.h>

#define D_MODEL 1024
#define NHEADS 16
#define DK 64
#define SEQ 2048
#define BATCH 2
#define MROWS (BATCH * SEQ)            // 4096

typedef __attribute__((ext_vector_type(8))) short bfrag8;   // 8 bf16 (4 VGPRs)
typedef __attribute__((ext_vector_type(4))) float f32x4;
typedef unsigned short u16;
typedef __attribute__((ext_vector_type(8))) u16 u16x8;
typedef __attribute__((ext_vector_type(4))) u16 u16x4;

#define GLOBAL_AS(p) ((const __attribute__((address_space(1))) void*)(p))
#define LDS_AS(p)    ((__attribute__((address_space(3))) void*)(p))

#define RAW_BARRIER()  __asm__ volatile("s_barrier" ::: "memory")
#define WAIT_VM8()     __asm__ volatile("s_waitcnt vmcnt(8)" ::: "memory")
#define WAIT_VM6()     __asm__ volatile("s_waitcnt vmcnt(6)" ::: "memory")
#define WAIT_VM4()     __asm__ volatile("s_waitcnt vmcnt(4)" ::: "memory")
#define WAIT_VM3()     __asm__ volatile("s_waitcnt vmcnt(3)" ::: "memory")
#define WAIT_VM0()     __asm__ volatile("s_waitcnt vmcnt(0)" ::: "memory")

__device__ inline u16 f2bf(float f) {
  union { float f; unsigned u; } c; c.f = f;
  unsigned r = c.u + 0x7FFF + ((c.u >> 16) & 1);   // RNE
  return (u16)(r >> 16);
}

// pack trunc-bf16(lo), trunc-bf16(hi) into one u32 with a single v_perm_b32
__device__ inline unsigned pack_bf2(float lo, float hi) {
  return __builtin_amdgcn_perm(__float_as_uint(hi), __float_as_uint(lo), 0x07060302);
}

// ---------------------------------------------------------------------------
// Fused fp32->bf16 conversion (x + 4 weights) AND RoPE cos/sin table build.
// Blocks [0, 8192): convert; blocks [8192, 8704): tab.
// ---------------------------------------------------------------------------
struct CvtPtrs { const float* src[5]; };

__global__ __launch_bounds__(256)
void convert_and_tab(CvtPtrs p, u16* __restrict__ dst,
                     const int* __restrict__ pos, float2* __restrict__ tab) {
  const int bi = blockIdx.x;
  if (bi < 8192) {
    size_t base = ((size_t)bi * 256 + threadIdx.x) * 4;
    const size_t XSZ = (size_t)MROWS * D_MODEL;
    const float* s; size_t off;
    if (base < XSZ) { s = p.src[0]; off = base; }
    else {
      size_t j = base - XSZ;
      s = p.src[1 + (int)(j >> 20)];
      off = j & ((1u << 20) - 1);
    }
    float4 v = *(const float4*)(s + off);
    u16 o[4] = { f2bf(v.x), f2bf(v.y), f2bf(v.z), f2bf(v.w) };
    *(u16x4*)(dst + base) = *(u16x4*)o;
  } else {
    int idx = (bi - 8192) * 256 + threadIdx.x;   // 131072 total
    int i = idx & 31, bs = idx >> 5;
    float pp = (float)pos[bs];
    float freq = expf(-(float)i * 0.2878231366242558f);  // ln(10000)/32
    float sn, cs;
    sincosf(pp * freq, &sn, &cs);
    tab[idx] = make_float2(cs, sn);
  }
}

// ---------------------------------------------------------------------------
// Shared bf16 MFMA NT-GEMM core, R17 (proven): 128x128 tile, BK=32, TRIPLE-
// buffered LDS, prefetch distance 2, counted vmcnt(8). Covers the ~500-900cyc
// L2/L3-miss latency that depth-1 (R14, null) could not.
// ---------------------------------------------------------------------------
__device__ inline void gemm_core(const u16* __restrict__ A, const u16* __restrict__ B,
                                 int m0, int n0, u16* As, u16* Bs,
                                 f32x4 acc[4][4]) {
  const int tid = threadIdx.x;
  const int w = tid >> 6, lane = tid & 63;
  const int l15 = lane & 15, quad = lane >> 4;
  const int wm = w >> 1, wn = w & 1;
  const int srow = tid >> 2;
  const int scol = (tid & 3) * 8;

  #pragma unroll
  for (int mi = 0; mi < 4; ++mi)
    #pragma unroll
    for (int ni = 0; ni < 4; ++ni) acc[mi][ni] = (f32x4)0.f;

  #define GSTAGE(T, BUF) do {                                                        \
    _Pragma("unroll")                                                                \
    for (int i_ = 0; i_ < 2; ++i_) {                                                 \
      const u16* ga_ = A + (size_t)((i_ * 64 + srow) + m0) * D_MODEL + (T) * 32 + scol; \
      const u16* gb_ = B + (size_t)((i_ * 64 + srow) + n0) * D_MODEL + (T) * 32 + scol; \
      __builtin_amdgcn_global_load_lds(GLOBAL_AS(ga_),                               \
          LDS_AS(&As[(BUF) * 4096 + (i_ * 64 + w * 16) * 32]), 16, 0, 0);            \
      __builtin_amdgcn_global_load_lds(GLOBAL_AS(gb_),                               \
          LDS_AS(&Bs[(BUF) * 4096 + (i_ * 64 + w * 16) * 32]), 16, 0, 0);            \
    }                                                                                \
  } while (0)

  const int NT = D_MODEL / 32;           // 32 K-steps
  GSTAGE(0, 0);
  GSTAGE(1, 1);
  int sbuf = 2;                          // buffer for tile t+2
  int cbuf = 0;                          // buffer for tile t
  for (int t = 0; t < NT; ++t) {
    RAW_BARRIER();                       // all waves done reading sbuf (tile t-1)
    if (t + 2 < NT) {
      GSTAGE(t + 2, sbuf);
      WAIT_VM8();                        // t's 4 loads done; t+1,t+2's 8 in flight
    } else if (t + 1 < NT) {
      WAIT_VM4();
    } else {
      WAIT_VM0();
    }
    RAW_BARRIER();                       // cbuf fully staged for all waves

    bfrag8 af[4], bfr[4];
    #pragma unroll
    for (int i = 0; i < 4; ++i) {
      af[i]  = *(const bfrag8*)&As[cbuf * 4096 + (wm * 64 + i * 16 + l15) * 32 + quad * 8];
      bfr[i] = *(const bfrag8*)&Bs[cbuf * 4096 + (wn * 64 + i * 16 + l15) * 32 + quad * 8];
    }
    #pragma unroll
    for (int mi = 0; mi < 4; ++mi)
      #pragma unroll
      for (int ni = 0; ni < 4; ++ni)
        acc[mi][ni] = __builtin_amdgcn_mfma_f32_16x16x32_bf16(af[mi], bfr[ni], acc[mi][ni], 0, 0, 0);

    sbuf = cbuf;
    cbuf = (cbuf == 2) ? 0 : cbuf + 1;
  }
  #undef GSTAGE
}

// ---------------------------------------------------------------------------
// Fused QKV GEMM (R17, unchanged).
// ---------------------------------------------------------------------------
struct QKVArgs { const u16* A[3]; const u16* B[3]; u16* dst[3]; const float2* tab; };

__global__ __launch_bounds__(256)
void gemm_qkv_fused(QKVArgs p) {
  __shared__ u16 As[3 * 128 * 32];       // 24KB (triple-buffered)
  __shared__ u16 Bs[3 * 128 * 32];       // 24KB
  const int z = blockIdx.z;
  const int bi = blockIdx.x;
  int m0, n0;
  if (z < 2) { m0 = (bi & 7) * 128; n0 = (bi >> 3) * 128; }   // M=1024 dims, N=4096 s
  else       { m0 = (bi >> 3) * 128; n0 = (bi & 7) * 128; }   // M=4096 s, N=1024 dims
  f32x4 acc[4][4];
  gemm_core(p.A[z], p.B[z], m0, n0, As, Bs, acc);

  const int tid = threadIdx.x;
  const int w = tid >> 6, lane = tid & 63;
  const int l15 = lane & 15, quad = lane >> 4;
  const int wm = w >> 1, wn = w & 1;
  u16* dst = p.dst[z];

  if (z < 2) {
    const int head = (m0 + wm * 64) >> 6;
    const float scale = (z == 0) ? 0.125f * 1.4426950408889634f : 1.0f;
    #pragma unroll
    for (int ni = 0; ni < 4; ++ni) {
      int sg = n0 + wn * 64 + ni * 16 + l15;      // 0..4095
      int b = sg >> 11;
      int s = sg & (SEQ - 1);
      size_t ho = ((size_t)(b * NHEADS + head)) * SEQ * DK;
      #pragma unroll
      for (int mi = 0; mi < 4; ++mi) {
        float4 t = *(const float4*)&p.tab[(size_t)sg * 32 + mi * 8 + quad * 2];
        float e0 = acc[mi][ni][0], o0 = acc[mi][ni][1];
        float e1 = acc[mi][ni][2], o1 = acc[mi][ni][3];
        u16x4 ov = { f2bf((e0 * t.x - o0 * t.y) * scale),
                     f2bf((e0 * t.y + o0 * t.x) * scale),
                     f2bf((e1 * t.z - o1 * t.w) * scale),
                     f2bf((e1 * t.w + o1 * t.z) * scale) };
        *(u16x4*)&dst[ho + (size_t)s * DK + mi * 16 + quad * 4] = ov;
      }
    }
  } else {
    const int b = m0 >> 11;
    const int head = (n0 >> 6) + wn;
    const size_t ho = ((size_t)(b * NHEADS + head)) * SEQ * DK;
    const int row_base = m0 + wm * 64;
    #pragma unroll
    for (int mi = 0; mi < 4; ++mi)
      #pragma unroll
      for (int ni = 0; ni < 4; ++ni) {
        int d = ni * 16 + l15;
        int sb = (row_base + mi * 16 + quad * 4) & (SEQ - 1);
        u16 o[4];
        #pragma unroll
        for (int r = 0; r < 4; ++r) o[r] = f2bf(acc[mi][ni][r]);
        *(u16x4*)&dst[ho + (size_t)d * SEQ + sb] = *(u16x4*)o;
      }
  }
}

// ---------------------------------------------------------------------------
// Output projection GEMM, R18: 128x64 tile (512 blocks) + R17 depth-2
// triple-buffer (3 loads/stage -> vmcnt(6)/(3)/(0)). LDS 36KB.
// ---------------------------------------------------------------------------
__global__ __launch_bounds__(256)
void gemm_out_bf16(const u16* __restrict__ A, const u16* __restrict__ B,
                   float* __restrict__ C) {
  __shared__ u16 As[3 * 128 * 32];       // 24KB
  __shared__ u16 Bs[3 * 64 * 32];        // 12KB
  const int m0 = blockIdx.y * 128, n0 = blockIdx.x * 64;
  const int tid = threadIdx.x;
  const int w = tid >> 6, lane = tid & 63;
  const int l15 = lane & 15, quad = lane >> 4;
  const int wm = w >> 1, wn = w & 1;
  const int lrow = lane >> 2;
  const int lcol = (lane & 3) * 8;

  f32x4 acc[4][2];
  #pragma unroll
  for (int mi = 0; mi < 4; ++mi)
    #pragma unroll
    for (int ni = 0; ni < 2; ++ni) acc[mi][ni] = (f32x4)0.f;

  #define OSTAGE(T, BUF) do {                                                        \
    _Pragma("unroll")                                                                \
    for (int i_ = 0; i_ < 2; ++i_) {                                                 \
      int row_ = (i_ * 4 + w) * 16 + lrow;                                           \
      const u16* ga_ = A + (size_t)(m0 + row_) * D_MODEL + (T) * 32 + lcol;          \
      __builtin_amdgcn_global_load_lds(GLOBAL_AS(ga_),                               \
          LDS_AS(&As[(BUF) * 4096 + (i_ * 4 + w) * 16 * 32]), 16, 0, 0);             \
    }                                                                                \
    {                                                                                \
      int row_ = w * 16 + lrow;                                                      \
      const u16* gb_ = B + (size_t)(n0 + row_) * D_MODEL + (T) * 32 + lcol;          \
      __builtin_amdgcn_global_load_lds(GLOBAL_AS(gb_),                               \
          LDS_AS(&Bs[(BUF) * 2048 + w * 16 * 32]), 16, 0, 0);                        \
    }                                                                                \
  } while (0)

  const int NT = D_MODEL / 32;
  OSTAGE(0, 0);
  OSTAGE(1, 1);
  int sbuf = 2, cbuf = 0;
  for (int t = 0; t < NT; ++t) {
    RAW_BARRIER();
    if (t + 2 < NT) {
      OSTAGE(t + 2, sbuf);
      WAIT_VM6();
    } else if (t + 1 < NT) {
      WAIT_VM3();
    } else {
      WAIT_VM0();
    }
    RAW_BARRIER();

    bfrag8 af[4], bfr[2];
    #pragma unroll
    for (int i = 0; i < 4; ++i)
      af[i] = *(const bfrag8*)&As[cbuf * 4096 + (wm * 64 + i * 16 + l15) * 32 + quad * 8];
    #pragma unroll
    for (int i = 0; i < 2; ++i)
      bfr[i] = *(const bfrag8*)&Bs[cbuf * 2048 + (wn * 32 + i * 16 + l15) * 32 + quad * 8];
    #pragma unroll
    for (int mi = 0; mi < 4; ++mi)
      #pragma unroll
      for (int ni = 0; ni < 2; ++ni)
        acc[mi][ni] = __builtin_amdgcn_mfma_f32_16x16x32_bf16(af[mi], bfr[ni], acc[mi][ni], 0, 0, 0);

    sbuf = cbuf;
    cbuf = (cbuf == 2) ? 0 : cbuf + 1;
  }
  #undef OSTAGE

  #pragma unroll
  for (int mi = 0; mi < 4; ++mi)
    #pragma unroll
    for (int ni = 0; ni < 2; ++ni)
      #pragma unroll
      for (int r = 0; r < 4; ++r) {
        int row = m0 + wm * 64 + mi * 16 + quad * 4 + r;
        int col = n0 + wn * 32 + ni * 16 + l15;
        C[(size_t)row * D_MODEL + col] = acc[mi][ni][r];
      }
}

// ---------------------------------------------------------------------------
// Flash attention, R18: split-half. R13's grid (1024 = exact capacity) had
// wall = max ntiles = 32 while avg = 16.5 -> slot util 51.6% (measured
// occupancy 25.6% == 16 waves x 0.516 -- exact). Fixed-base softmax (no
// running max) makes O = sum(VP), l = sum(p) PARTITION-COMMUTATIVE, so each
// q-tile's key range is split into two halves -> 2048 blocks (max 16 tiles),
// 5 blocks/CU LDS-resident, BACKFILL pool active. Each half writes
// unnormalized f32 O-partial + l-partial; attn_merge normalizes.
// Blocks with 0 tiles skip the initial STAGE (no orphaned in-flight LDS
// writes at endpgm). All range bounds are wave-uniform (barrier-safe).
// ---------------------------------------------------------------------------
__global__ __launch_bounds__(256, 4)
void attn_mfma(const u16* __restrict__ Qbf, const u16* __restrict__ Kbf,
               const u16* __restrict__ Vtb, float* __restrict__ Opart,
               float* __restrict__ lpart) {
  __shared__ u16 Ks[2][64 * 64];
  __shared__ u16 Vt[2][64 * 64];

  const int tid = threadIdx.x;
  const int w = tid >> 6, lane = tid & 63;
  const int l15 = lane & 15, quad = lane >> 4;

  const int bid = blockIdx.x;              // 0..2047
  const int hb = bid & 31;                 // XCD = hb % 8 -> head-local L2
  const int half = (bid >> 5) & 1;
  const int g = bid >> 6;                  // 0..31
  const int tt = (g & 7) | ((g & 16) >> 1);        // 0..15
  const int qt = (g & 8) ? (31 - tt) : tt;         // balanced diagonal pairing
  const size_t ho = (size_t)hb * SEQ * DK;
  const int qrow_base = qt * 64 + w * 16;

  const int n = qt + 1;
  const int mid = (n + 1) >> 1;
  const int lo = half ? mid : 0;
  const int hi = half ? n : mid;

  bfrag8 qf[2];
  #pragma unroll
  for (int hh = 0; hh < 2; ++hh)
    qf[hh] = *(const bfrag8*)&Qbf[ho + (size_t)(qrow_base + l15) * DK + hh * 32 + quad * 8];

  f32x4 oacc[4];
  float l_ = 0.f;
  #pragma unroll
  for (int n0 = 0; n0 < 4; ++n0) oacc[n0] = (f32x4)0.f;

  // staging: 256 threads, 2 rounds of 32 rows; one 16B chunk per row-slot.
  const int srow = w * 8 + (lane >> 3);              // 0..31
  const int scc = ((lane & 7) ^ (srow & 7)) * 8;     // XOR-swizzled col chunk

  // bpermute source-lane byte addresses: lane = (quad&1)*32 + (j>>1)*16 + l15
  const int adr0 = (((quad & 1) << 5) + l15) << 2;
  const int adr1 = adr0 + 64;

  #define STAGE(T, BUF) do {                                                         \
    int j0_ = (T) * 64;                                                              \
    _Pragma("unroll")                                                                \
    for (int r_ = 0; r_ < 2; ++r_) {                                                 \
      int row_ = r_ * 32 + srow;                                                     \
      __builtin_amdgcn_global_load_lds(GLOBAL_AS(Kbf + ho + (size_t)(j0_ + row_) * DK + scc), \
                                       LDS_AS(&Ks[BUF][(r_ * 32 + w * 8) * 64]), 16, 0, 0);   \
      __builtin_amdgcn_global_load_lds(GLOBAL_AS(Vtb + ho + (size_t)row_ * SEQ + j0_ + scc),  \
                                       LDS_AS(&Vt[BUF][(r_ * 32 + w * 8) * 64]), 16, 0, 0);   \
    }                                                                                \
  } while (0)

  if (hi > lo) {
    STAGE(lo, 0);
    for (int t = lo; t < hi; ++t) {
      const int j0 = t * 64;
      const int buf = (t - lo) & 1;
      RAW_BARRIER();                       // all waves done reading buf^1
      if (t + 1 < hi) {
        STAGE(t + 1, buf ^ 1);
        WAIT_VM4();                        // tile t's 4 loads done; t+1's in flight
      } else {
        WAIT_VM0();
      }
      RAW_BARRIER();                       // buf fully staged by all 4 waves

      // ---- S^T = K·Q^T ----
      f32x4 sc[4];
      const int sw = l15 & 7;
      #pragma unroll
      for (int st = 0; st < 4; ++st) {
        int key = st * 16 + l15;
        bfrag8 kf0 = *(const bfrag8*)&Ks[buf][key * 64 + ((quad ^ sw) * 8)];
        bfrag8 kf1 = *(const bfrag8*)&Ks[buf][key * 64 + (((4 + quad) ^ sw) * 8)];
        sc[st] = __builtin_amdgcn_mfma_f32_16x16x32_bf16(kf0, qf[0], (f32x4)0.f, 0, 0, 0);
        sc[st] = __builtin_amdgcn_mfma_f32_16x16x32_bf16(kf1, qf[1], sc[st], 0, 0, 0);
      }

      // ---- causal mask (diagonal tile only) ----
      if (j0 + 63 > qrow_base) {
        #pragma unroll
        for (int st = 0; st < 4; ++st)
          #pragma unroll
          for (int r = 0; r < 4; ++r) {
            int key = j0 + st * 16 + quad * 4 + r;
            if (key > qrow_base + l15) sc[st][r] = -60.f;
          }
      }

      // ---- fixed-base softmax: p = exp2(min(s,60)); pack to bf16 words ----
      unsigned pk[4][2];
      float rs = 0.f;
      #pragma unroll
      for (int st = 0; st < 4; ++st) {
        float p0 = __builtin_amdgcn_exp2f(fminf(sc[st][0], 60.f));
        float p1 = __builtin_amdgcn_exp2f(fminf(sc[st][1], 60.f));
        float p2 = __builtin_amdgcn_exp2f(fminf(sc[st][2], 60.f));
        float p3 = __builtin_amdgcn_exp2f(fminf(sc[st][3], 60.f));
        rs += (p0 + p1) + (p2 + p3);
        pk[st][0] = pack_bf2(p0, p1);
        pk[st][1] = pack_bf2(p2, p3);
      }
      l_ += rs;

      // ---- in-register quad exchange: S^T C-layout -> PV B-fragment ----
      union PU { bfrag8 f; int i[4]; } u0, u1;
      #pragma unroll
      for (int j = 0; j < 4; ++j) {
        const int adr = (j & 2) ? adr1 : adr0;
        int lo0 = __builtin_amdgcn_ds_bpermute(adr, (int)pk[0][j & 1]);
        int hi0 = __builtin_amdgcn_ds_bpermute(adr, (int)pk[1][j & 1]);
        int lo1 = __builtin_amdgcn_ds_bpermute(adr, (int)pk[2][j & 1]);
        int hi1 = __builtin_amdgcn_ds_bpermute(adr, (int)pk[3][j & 1]);
        u0.i[j] = (quad & 2) ? hi0 : lo0;
        u1.i[j] = (quad & 2) ? hi1 : lo1;
      }
      bfrag8 pf[2] = { u0.f, u1.f };

      // ---- O^T += V^T·P ----
      #pragma unroll
      for (int n0 = 0; n0 < 4; ++n0) {
        #pragma unroll
        for (int kc = 0; kc < 2; ++kc) {
          bfrag8 vf = *(const bfrag8*)&Vt[buf][(n0 * 16 + l15) * 64 + (((kc * 4 + quad) ^ sw) * 8)];
          oacc[n0] = __builtin_amdgcn_mfma_f32_16x16x32_bf16(vf, pf[kc], oacc[n0], 0, 0, 0);
        }
      }
    }
  }
  #undef STAGE

  // ---- epilogue: reduce l across quads; store UNNORMALIZED f32 partials ----
  float l = l_;
  l += __shfl_xor(l, 16);
  l += __shfl_xor(l, 32);
  int q = qrow_base + l15;
  float* Op = Opart + ((size_t)(half * 32 + hb) * SEQ + q) * DK;
  #pragma unroll
  for (int n0 = 0; n0 < 4; ++n0)
    *(f32x4*)&Op[n0 * 16 + quad * 4] = oacc[n0];
  if (quad == 0)
    lpart[(size_t)(half * 32 + hb) * SEQ + q] = l;
}

// ---------------------------------------------------------------------------
// Merge: obb[q, h*64+d] = (O1 + O2) / (l1 + l2), f32 -> bf16.
// 1,048,576 threads (4096 blocks x 256): idx = (hb, q, d-quad).
// ---------------------------------------------------------------------------
__global__ __launch_bounds__(256)
void attn_merge(const float* __restrict__ Opart, const float* __restrict__ lpart,
                u16* __restrict__ obb) {
  int idx = blockIdx.x * 256 + threadIdx.x;
  int t = idx & 15;                    // d-quad: d = t*4 .. t*4+3
  int q = (idx >> 4) & (SEQ - 1);
  int hb = idx >> 15;                  // 0..31
  int b = hb >> 4, h = hb & 15;
  float l = lpart[(size_t)hb * SEQ + q] + lpart[(size_t)(32 + hb) * SEQ + q];
  float inv = 1.f / l;
  f32x4 a = *(const f32x4*)(Opart + ((size_t)hb * SEQ + q) * DK + t * 4);
  f32x4 c = *(const f32x4*)(Opart + ((size_t)(32 + hb) * SEQ + q) * DK + t * 4);
  u16x4 ov = { f2bf((a[0] + c[0]) * inv), f2bf((a[1] + c[1]) * inv),
               f2bf((a[2] + c[2]) * inv), f2bf((a[3] + c[3]) * inv) };
  *(u16x4*)&obb[((size_t)(b * SEQ + q)) * D_MODEL + h * DK + t * 4] = ov;
}

// ---------------------------------------------------------------------------
extern "C" void kernel_launch(void* const* d_in, const int* in_sizes, int n_in,
                              void* d_out, int out_size, void* d_ws, size_t ws_size,
                              hipStream_t stream) {
  const float* x  = (const float*)d_in[0];
  const float* Wq = (const float*)d_in[1];
  const float* Wk = (const float*)d_in[2];
  const float* Wv = (const float*)d_in[3];
  const float* Wo = (const float*)d_in[4];
  const int* pos  = (const int*)d_in[5];

  const size_t XSZ = (size_t)MROWS * D_MODEL;   // 4M elems
  const size_t WSZ = (size_t)D_MODEL * D_MODEL; // 1M elems

  u16* bfb = (u16*)d_ws;
  u16* xb  = bfb;                     // 4M
  u16* wqb = xb  + XSZ;
  u16* wkb = wqb + WSZ;
  u16* wvb = wkb + WSZ;
  u16* wob = wvb + WSZ;
  u16* Qbf = wob + WSZ;               // 4M  [b,h,s,64]
  u16* Kbf = Qbf + XSZ;               // 4M  [b,h,s,64]
  u16* Vtb = Kbf + XSZ;               // 4M  [b,h,64,s]
  u16* obb = Vtb + XSZ;               // 4M  [b*s, h*64]
  float2* tab = (float2*)(obb + XSZ); // 131072 float2 (1MB)
  float* Opart = (float*)(tab + 131072);          // 2*32*2048*64 f32 = 32MB
  float* lpart = Opart + (size_t)2 * 32 * SEQ * DK; // 2*32*2048 f32 = 512KB

  // 1. convert x + weights to bf16, and build RoPE table (fused)
  CvtPtrs cp; cp.src[0] = x; cp.src[1] = Wq; cp.src[2] = Wk; cp.src[3] = Wv; cp.src[4] = Wo;
  convert_and_tab<<<8192 + 512, 256, 0, stream>>>(cp, xb, pos, tab);

  // 2. QKV projections with fused RoPE/repack/V-transpose epilogue
  QKVArgs qp;
  qp.A[0] = wqb; qp.A[1] = wkb; qp.A[2] = xb;
  qp.B[0] = xb;  qp.B[1] = xb;  qp.B[2] = wvb;
  qp.dst[0] = Qbf; qp.dst[1] = Kbf; qp.dst[2] = Vtb;
  qp.tab = tab;
  gemm_qkv_fused<<<dim3(256, 1, 3), 256, 0, stream>>>(qp);

  // 3. flash attention: 2048 split-half blocks (backfill) -> f32 partials
  attn_mfma<<<dim3(2048), 256, 0, stream>>>(Qbf, Kbf, Vtb, Opart, lpart);

  // 3b. merge halves, normalize, cast to bf16 obb
  attn_merge<<<dim3(4096), 256, 0, stream>>>(Opart, lpart, obb);

  // 4. output projection (128x64 tiles, 512 blocks, depth-2 pipeline)
  gemm_out_bf16<<<dim3(D_MODEL / 64, MROWS / 128), 256, 0, stream>>>(obb, wob, (float*)d_out);
}

// Round 9
// 179.834 us; speedup vs baseline: 1.0490x; 1.0490x over previous
//
#include <hip/hip_runtime.h>
#include <math.h>

#define D_MODEL 1024
#define NHEADS 16
#define DK 64
#define SEQ 2048
#define BATCH 2
#define MROWS (BATCH * SEQ)            // 4096

typedef __attribute__((ext_vector_type(8))) short bfrag8;   // 8 bf16 (4 VGPRs)
typedef __attribute__((ext_vector_type(4))) float f32x4;
typedef unsigned short u16;
typedef __attribute__((ext_vector_type(8))) u16 u16x8;
typedef __attribute__((ext_vector_type(4))) u16 u16x4;

#define GLOBAL_AS(p) ((const __attribute__((address_space(1))) void*)(p))
#define LDS_AS(p)    ((__attribute__((address_space(3))) void*)(p))

#define RAW_BARRIER()  __asm__ volatile("s_barrier" ::: "memory")
#define WAIT_VM8()     __asm__ volatile("s_waitcnt vmcnt(8)" ::: "memory")
#define WAIT_VM4()     __asm__ volatile("s_waitcnt vmcnt(4)" ::: "memory")
#define WAIT_VM2()     __asm__ volatile("s_waitcnt vmcnt(2)" ::: "memory")
#define WAIT_VM0()     __asm__ volatile("s_waitcnt vmcnt(0)" ::: "memory")

__device__ inline u16 f2bf(float f) {
  union { float f; unsigned u; } c; c.f = f;
  unsigned r = c.u + 0x7FFF + ((c.u >> 16) & 1);   // RNE
  return (u16)(r >> 16);
}

// pack trunc-bf16(lo), trunc-bf16(hi) into one u32 with a single v_perm_b32
__device__ inline unsigned pack_bf2(float lo, float hi) {
  return __builtin_amdgcn_perm(__float_as_uint(hi), __float_as_uint(lo), 0x07060302);
}

// ---------------------------------------------------------------------------
// Fused fp32->bf16 conversion (x + 4 weights) AND RoPE cos/sin table build.
// Blocks [0, 8192): convert; blocks [8192, 8704): tab.
// ---------------------------------------------------------------------------
struct CvtPtrs { const float* src[5]; };

__global__ __launch_bounds__(256)
void convert_and_tab(CvtPtrs p, u16* __restrict__ dst,
                     const int* __restrict__ pos, float2* __restrict__ tab) {
  const int bi = blockIdx.x;
  if (bi < 8192) {
    size_t base = ((size_t)bi * 256 + threadIdx.x) * 4;
    const size_t XSZ = (size_t)MROWS * D_MODEL;
    const float* s; size_t off;
    if (base < XSZ) { s = p.src[0]; off = base; }
    else {
      size_t j = base - XSZ;
      s = p.src[1 + (int)(j >> 20)];
      off = j & ((1u << 20) - 1);
    }
    float4 v = *(const float4*)(s + off);
    u16 o[4] = { f2bf(v.x), f2bf(v.y), f2bf(v.z), f2bf(v.w) };
    *(u16x4*)(dst + base) = *(u16x4*)o;
  } else {
    int idx = (bi - 8192) * 256 + threadIdx.x;   // 131072 total
    int i = idx & 31, bs = idx >> 5;
    float pp = (float)pos[bs];
    float freq = expf(-(float)i * 0.2878231366242558f);  // ln(10000)/32
    float sn, cs;
    sincosf(pp * freq, &sn, &cs);
    tab[idx] = make_float2(cs, sn);
  }
}

// ---------------------------------------------------------------------------
// Shared bf16 MFMA NT-GEMM core, R17 (proven): 128x128 tile, BK=32, TRIPLE-
// buffered LDS, prefetch distance 2, counted vmcnt(8). Covers the ~500-900cyc
// L2/L3-miss latency that depth-1 (R14, null) could not.
// ---------------------------------------------------------------------------
__device__ inline void gemm_core(const u16* __restrict__ A, const u16* __restrict__ B,
                                 int m0, int n0, u16* As, u16* Bs,
                                 f32x4 acc[4][4]) {
  const int tid = threadIdx.x;
  const int w = tid >> 6, lane = tid & 63;
  const int l15 = lane & 15, quad = lane >> 4;
  const int wm = w >> 1, wn = w & 1;
  const int srow = tid >> 2;
  const int scol = (tid & 3) * 8;

  #pragma unroll
  for (int mi = 0; mi < 4; ++mi)
    #pragma unroll
    for (int ni = 0; ni < 4; ++ni) acc[mi][ni] = (f32x4)0.f;

  #define GSTAGE(T, BUF) do {                                                        \
    _Pragma("unroll")                                                                \
    for (int i_ = 0; i_ < 2; ++i_) {                                                 \
      const u16* ga_ = A + (size_t)((i_ * 64 + srow) + m0) * D_MODEL + (T) * 32 + scol; \
      const u16* gb_ = B + (size_t)((i_ * 64 + srow) + n0) * D_MODEL + (T) * 32 + scol; \
      __builtin_amdgcn_global_load_lds(GLOBAL_AS(ga_),                               \
          LDS_AS(&As[(BUF) * 4096 + (i_ * 64 + w * 16) * 32]), 16, 0, 0);            \
      __builtin_amdgcn_global_load_lds(GLOBAL_AS(gb_),                               \
          LDS_AS(&Bs[(BUF) * 4096 + (i_ * 64 + w * 16) * 32]), 16, 0, 0);            \
    }                                                                                \
  } while (0)

  const int NT = D_MODEL / 32;           // 32 K-steps
  GSTAGE(0, 0);
  GSTAGE(1, 1);
  int sbuf = 2;                          // buffer for tile t+2
  int cbuf = 0;                          // buffer for tile t
  for (int t = 0; t < NT; ++t) {
    RAW_BARRIER();                       // all waves done reading sbuf (tile t-1)
    if (t + 2 < NT) {
      GSTAGE(t + 2, sbuf);
      WAIT_VM8();                        // t's 4 loads done; t+1,t+2's 8 in flight
    } else if (t + 1 < NT) {
      WAIT_VM4();
    } else {
      WAIT_VM0();
    }
    RAW_BARRIER();                       // cbuf fully staged for all waves

    bfrag8 af[4], bfr[4];
    #pragma unroll
    for (int i = 0; i < 4; ++i) {
      af[i]  = *(const bfrag8*)&As[cbuf * 4096 + (wm * 64 + i * 16 + l15) * 32 + quad * 8];
      bfr[i] = *(const bfrag8*)&Bs[cbuf * 4096 + (wn * 64 + i * 16 + l15) * 32 + quad * 8];
    }
    #pragma unroll
    for (int mi = 0; mi < 4; ++mi)
      #pragma unroll
      for (int ni = 0; ni < 4; ++ni)
        acc[mi][ni] = __builtin_amdgcn_mfma_f32_16x16x32_bf16(af[mi], bfr[ni], acc[mi][ni], 0, 0, 0);

    sbuf = cbuf;
    cbuf = (cbuf == 2) ? 0 : cbuf + 1;
  }
  #undef GSTAGE
}

// ---------------------------------------------------------------------------
// Fused QKV GEMM (R17, unchanged).
// ---------------------------------------------------------------------------
struct QKVArgs { const u16* A[3]; const u16* B[3]; u16* dst[3]; const float2* tab; };

__global__ __launch_bounds__(256)
void gemm_qkv_fused(QKVArgs p) {
  __shared__ u16 As[3 * 128 * 32];       // 24KB (triple-buffered)
  __shared__ u16 Bs[3 * 128 * 32];       // 24KB
  const int z = blockIdx.z;
  const int bi = blockIdx.x;
  int m0, n0;
  if (z < 2) { m0 = (bi & 7) * 128; n0 = (bi >> 3) * 128; }   // M=1024 dims, N=4096 s
  else       { m0 = (bi >> 3) * 128; n0 = (bi & 7) * 128; }   // M=4096 s, N=1024 dims
  f32x4 acc[4][4];
  gemm_core(p.A[z], p.B[z], m0, n0, As, Bs, acc);

  const int tid = threadIdx.x;
  const int w = tid >> 6, lane = tid & 63;
  const int l15 = lane & 15, quad = lane >> 4;
  const int wm = w >> 1, wn = w & 1;
  u16* dst = p.dst[z];

  if (z < 2) {
    const int head = (m0 + wm * 64) >> 6;
    const float scale = (z == 0) ? 0.125f * 1.4426950408889634f : 1.0f;
    #pragma unroll
    for (int ni = 0; ni < 4; ++ni) {
      int sg = n0 + wn * 64 + ni * 16 + l15;      // 0..4095
      int b = sg >> 11;
      int s = sg & (SEQ - 1);
      size_t ho = ((size_t)(b * NHEADS + head)) * SEQ * DK;
      #pragma unroll
      for (int mi = 0; mi < 4; ++mi) {
        float4 t = *(const float4*)&p.tab[(size_t)sg * 32 + mi * 8 + quad * 2];
        float e0 = acc[mi][ni][0], o0 = acc[mi][ni][1];
        float e1 = acc[mi][ni][2], o1 = acc[mi][ni][3];
        u16x4 ov = { f2bf((e0 * t.x - o0 * t.y) * scale),
                     f2bf((e0 * t.y + o0 * t.x) * scale),
                     f2bf((e1 * t.z - o1 * t.w) * scale),
                     f2bf((e1 * t.w + o1 * t.z) * scale) };
        *(u16x4*)&dst[ho + (size_t)s * DK + mi * 16 + quad * 4] = ov;
      }
    }
  } else {
    const int b = m0 >> 11;
    const int head = (n0 >> 6) + wn;
    const size_t ho = ((size_t)(b * NHEADS + head)) * SEQ * DK;
    const int row_base = m0 + wm * 64;
    #pragma unroll
    for (int mi = 0; mi < 4; ++mi)
      #pragma unroll
      for (int ni = 0; ni < 4; ++ni) {
        int d = ni * 16 + l15;
        int sb = (row_base + mi * 16 + quad * 4) & (SEQ - 1);
        u16 o[4];
        #pragma unroll
        for (int r = 0; r < 4; ++r) o[r] = f2bf(acc[mi][ni][r]);
        *(u16x4*)&dst[ho + (size_t)d * SEQ + sb] = *(u16x4*)o;
      }
  }
}

// ---------------------------------------------------------------------------
// Output projection GEMM: 128x64 tile (512 blocks). R2 form (proven in the
// 180.9us best run; both dbuf variants were neutral-to-negative).
// ---------------------------------------------------------------------------
__global__ __launch_bounds__(256)
void gemm_out_bf16(const u16* __restrict__ A, const u16* __restrict__ B,
                   float* __restrict__ C) {
  __shared__ u16 As[128 * 32];
  __shared__ u16 Bs[64 * 32];
  const int m0 = blockIdx.y * 128, n0 = blockIdx.x * 64;
  const int tid = threadIdx.x;
  const int w = tid >> 6, lane = tid & 63;
  const int l15 = lane & 15, quad = lane >> 4;
  const int wm = w >> 1, wn = w & 1;
  const int lrow = lane >> 2;
  const int lcol = (lane & 3) * 8;

  f32x4 acc[4][2];
  #pragma unroll
  for (int mi = 0; mi < 4; ++mi)
    #pragma unroll
    for (int ni = 0; ni < 2; ++ni) acc[mi][ni] = (f32x4)0.f;

  for (int k0 = 0; k0 < D_MODEL; k0 += 32) {
    __syncthreads();
    #pragma unroll
    for (int i = 0; i < 2; ++i) {
      int row = (i * 4 + w) * 16 + lrow;
      const u16* ga = A + (size_t)(m0 + row) * D_MODEL + k0 + lcol;
      __builtin_amdgcn_global_load_lds(GLOBAL_AS(ga), LDS_AS(&As[(i * 4 + w) * 16 * 32]), 16, 0, 0);
    }
    {
      int row = w * 16 + lrow;
      const u16* gb = B + (size_t)(n0 + row) * D_MODEL + k0 + lcol;
      __builtin_amdgcn_global_load_lds(GLOBAL_AS(gb), LDS_AS(&Bs[w * 16 * 32]), 16, 0, 0);
    }
    __syncthreads();

    bfrag8 af[4], bfr[2];
    #pragma unroll
    for (int i = 0; i < 4; ++i)
      af[i] = *(const bfrag8*)&As[(wm * 64 + i * 16 + l15) * 32 + quad * 8];
    #pragma unroll
    for (int i = 0; i < 2; ++i)
      bfr[i] = *(const bfrag8*)&Bs[(wn * 32 + i * 16 + l15) * 32 + quad * 8];
    #pragma unroll
    for (int mi = 0; mi < 4; ++mi)
      #pragma unroll
      for (int ni = 0; ni < 2; ++ni)
        acc[mi][ni] = __builtin_amdgcn_mfma_f32_16x16x32_bf16(af[mi], bfr[ni], acc[mi][ni], 0, 0, 0);
  }

  #pragma unroll
  for (int mi = 0; mi < 4; ++mi)
    #pragma unroll
    for (int ni = 0; ni < 2; ++ni)
      #pragma unroll
      for (int r = 0; r < 4; ++r) {
        int row = m0 + wm * 64 + mi * 16 + quad * 4 + r;
        int col = n0 + wn * 32 + ni * 16 + l15;
        C[(size_t)row * D_MODEL + col] = acc[mi][ni][r];
      }
}

// ---------------------------------------------------------------------------
// Flash attention, R19: 8-wave KEY-SPLIT blocks. R13 was latency-bound with
// 16/32 wave slots used (per-wave issue ~30%; LDS residency caps blocks at
// 4/CU). Same 1024 blocks & 32KB K/V tiles, but 512 threads: wave (wq,kh)
// handles q-rows qt*64+wq*16 x keys kh*32..+31 -> per-wave work halves,
// 32 waves/CU resident. Each wave accumulates partial O/l over all tiles
// (key-split partials commute); one LDS merge per block at the end (kh=1
// writes O/l into the dead Ks/Vt buffers, kh=0 adds + normalizes + stores).
// Fragment algebra = R13's verified mappings restricted to the kc=0 slice;
// staging swizzle unchanged (row&7 invariant under kh*32).
// ---------------------------------------------------------------------------
__global__ __launch_bounds__(512, 8)
void attn_mfma(const u16* __restrict__ Qbf, const u16* __restrict__ Kbf,
               const u16* __restrict__ Vtb, u16* __restrict__ obb) {
  __shared__ u16 Ks[2][64 * 64];
  __shared__ u16 Vt[2][64 * 64];

  const int tid = threadIdx.x;
  const int w = tid >> 6, lane = tid & 63;
  const int l15 = lane & 15, quad = lane >> 4;
  const int wq = w & 3, kh = w >> 2;

  const int bid = blockIdx.x;
  const int hb = bid & 31;                 // XCD = hb % 8 -> head-local L2
  const int g  = bid >> 5;                 // 0..31
  const int tt = (g & 7) | ((g & 16) >> 1);        // 0..15
  const int qt = (g & 8) ? (31 - tt) : tt;         // balanced diagonal pairing
  const int b = hb >> 4, h = hb & 15;
  const size_t ho = (size_t)hb * SEQ * DK;
  const int qrow_base = qt * 64 + wq * 16;

  bfrag8 qf[2];
  #pragma unroll
  for (int hh = 0; hh < 2; ++hh)
    qf[hh] = *(const bfrag8*)&Qbf[ho + (size_t)(qrow_base + l15) * DK + hh * 32 + quad * 8];

  f32x4 oacc[4];
  float l_ = 0.f;
  #pragma unroll
  for (int n0 = 0; n0 < 4; ++n0) oacc[n0] = (f32x4)0.f;

  // staging: 512 threads cover the full 64x64 tile; 1 K + 1 V chunk each.
  const int srow = w * 8 + (lane >> 3);              // 0..63
  const int scc = ((lane & 7) ^ ((lane >> 3) & 7)) * 8;  // XOR-swizzled chunk

  // bpermute source-lane byte addresses: lane = (quad&1)*32 + (j>>1)*16 + l15
  const int adr0 = (((quad & 1) << 5) + l15) << 2;
  const int adr1 = adr0 + 64;

  #define STAGE(T, BUF) do {                                                         \
    int j0_ = (T) * 64;                                                              \
    __builtin_amdgcn_global_load_lds(GLOBAL_AS(Kbf + ho + (size_t)(j0_ + srow) * DK + scc), \
                                     LDS_AS(&Ks[BUF][w * 512]), 16, 0, 0);           \
    __builtin_amdgcn_global_load_lds(GLOBAL_AS(Vtb + ho + (size_t)srow * SEQ + j0_ + scc),  \
                                     LDS_AS(&Vt[BUF][w * 512]), 16, 0, 0);           \
  } while (0)

  const int ntiles = qt + 1;
  STAGE(0, 0);

  for (int t = 0; t < ntiles; ++t) {
    const int j0 = t * 64;
    const int buf = t & 1;
    RAW_BARRIER();                         // all waves done reading buf^1 (tile t-1)
    if (t + 1 < ntiles) {
      STAGE(t + 1, buf ^ 1);
      WAIT_VM2();                          // tile t's 2 loads complete; t+1's in flight
    } else {
      WAIT_VM0();
    }
    RAW_BARRIER();                         // buf fully staged by all 8 waves

    // ---- S^T = K·Q^T (this wave's 32 keys x its 16 q-rows) ----
    f32x4 sc[2];
    const int sw = l15 & 7;
    #pragma unroll
    for (int st = 0; st < 2; ++st) {
      int key = kh * 32 + st * 16 + l15;
      bfrag8 kf0 = *(const bfrag8*)&Ks[buf][key * 64 + ((quad ^ sw) * 8)];
      bfrag8 kf1 = *(const bfrag8*)&Ks[buf][key * 64 + (((4 + quad) ^ sw) * 8)];
      sc[st] = __builtin_amdgcn_mfma_f32_16x16x32_bf16(kf0, qf[0], (f32x4)0.f, 0, 0, 0);
      sc[st] = __builtin_amdgcn_mfma_f32_16x16x32_bf16(kf1, qf[1], sc[st], 0, 0, 0);
    }

    // ---- causal mask (diagonal-touching tiles; wave-uniform condition) ----
    if (j0 + 63 > qrow_base) {
      #pragma unroll
      for (int st = 0; st < 2; ++st)
        #pragma unroll
        for (int r = 0; r < 4; ++r) {
          int key = j0 + kh * 32 + st * 16 + quad * 4 + r;
          if (key > qrow_base + l15) sc[st][r] = -60.f;
        }
    }

    // ---- fixed-base softmax: p = exp2(min(s,60)); pack to bf16 words ----
    unsigned pk[2][2];
    float rs = 0.f;
    #pragma unroll
    for (int st = 0; st < 2; ++st) {
      float p0 = __builtin_amdgcn_exp2f(fminf(sc[st][0], 60.f));
      float p1 = __builtin_amdgcn_exp2f(fminf(sc[st][1], 60.f));
      float p2 = __builtin_amdgcn_exp2f(fminf(sc[st][2], 60.f));
      float p3 = __builtin_amdgcn_exp2f(fminf(sc[st][3], 60.f));
      rs += (p0 + p1) + (p2 + p3);
      pk[st][0] = pack_bf2(p0, p1);
      pk[st][1] = pack_bf2(p2, p3);
    }
    l_ += rs;

    // ---- in-register quad exchange: S^T C-layout -> PV B-fragment ----
    // (kc=0 slice of the R13-verified mapping; 8 bpermute + 4 cndmask)
    union PU { bfrag8 f; int i[4]; } u0;
    #pragma unroll
    for (int j = 0; j < 4; ++j) {
      const int adr = (j & 2) ? adr1 : adr0;
      int lo0 = __builtin_amdgcn_ds_bpermute(adr, (int)pk[0][j & 1]);
      int hi0 = __builtin_amdgcn_ds_bpermute(adr, (int)pk[1][j & 1]);
      u0.i[j] = (quad & 2) ? hi0 : lo0;
    }
    bfrag8 pf = u0.f;

    // ---- O^T += V^T·P (K=32: this wave's key half) ----
    #pragma unroll
    for (int n0 = 0; n0 < 4; ++n0) {
      bfrag8 vf = *(const bfrag8*)&Vt[buf][(n0 * 16 + l15) * 64 + (((kh * 4 + quad) ^ sw) * 8)];
      oacc[n0] = __builtin_amdgcn_mfma_f32_16x16x32_bf16(vf, pf, oacc[n0], 0, 0, 0);
    }
  }
  #undef STAGE

  // ---- epilogue: quad-reduce l; merge kh halves via LDS; store ----
  float l = l_;
  l += __shfl_xor(l, 16);
  l += __shfl_xor(l, 32);

  RAW_BARRIER();                           // all waves done reading K/V LDS
  float* osc = (float*)Ks;                 // 4 waves x 64 lanes x 16 f = 16KB
  float* lsc = (float*)Vt;                 // 4 x 16 f
  if (kh == 1) {
    #pragma unroll
    for (int n0 = 0; n0 < 4; ++n0)
      *(f32x4*)&osc[(wq * 64 + lane) * 16 + n0 * 4] = oacc[n0];
    if (quad == 0) lsc[wq * 16 + l15] = l;
  }
  RAW_BARRIER();
  if (kh == 0) {
    float lt = l + lsc[wq * 16 + l15];
    float inv = 1.f / lt;
    int q = qrow_base + l15;
    #pragma unroll
    for (int n0 = 0; n0 < 4; ++n0) {
      f32x4 o2 = *(const f32x4*)&osc[(wq * 64 + lane) * 16 + n0 * 4];
      u16x4 ov = { f2bf((oacc[n0][0] + o2[0]) * inv), f2bf((oacc[n0][1] + o2[1]) * inv),
                   f2bf((oacc[n0][2] + o2[2]) * inv), f2bf((oacc[n0][3] + o2[3]) * inv) };
      *(u16x4*)&obb[(size_t)(b * SEQ + q) * D_MODEL + h * DK + n0 * 16 + quad * 4] = ov;
    }
  }
}

// ---------------------------------------------------------------------------
extern "C" void kernel_launch(void* const* d_in, const int* in_sizes, int n_in,
                              void* d_out, int out_size, void* d_ws, size_t ws_size,
                              hipStream_t stream) {
  const float* x  = (const float*)d_in[0];
  const float* Wq = (const float*)d_in[1];
  const float* Wk = (const float*)d_in[2];
  const float* Wv = (const float*)d_in[3];
  const float* Wo = (const float*)d_in[4];
  const int* pos  = (const int*)d_in[5];

  const size_t XSZ = (size_t)MROWS * D_MODEL;   // 4M elems
  const size_t WSZ = (size_t)D_MODEL * D_MODEL; // 1M elems

  u16* bfb = (u16*)d_ws;
  u16* xb  = bfb;                     // 4M
  u16* wqb = xb  + XSZ;
  u16* wkb = wqb + WSZ;
  u16* wvb = wkb + WSZ;
  u16* wob = wvb + WSZ;
  u16* Qbf = wob + WSZ;               // 4M  [b,h,s,64]
  u16* Kbf = Qbf + XSZ;               // 4M  [b,h,s,64]
  u16* Vtb = Kbf + XSZ;               // 4M  [b,h,64,s]
  u16* obb = Vtb + XSZ;               // 4M  [b*s, h*64]
  float2* tab = (float2*)(obb + XSZ); // 131072 float2

  // 1. convert x + weights to bf16, and build RoPE table (fused)
  CvtPtrs cp; cp.src[0] = x; cp.src[1] = Wq; cp.src[2] = Wk; cp.src[3] = Wv; cp.src[4] = Wo;
  convert_and_tab<<<8192 + 512, 256, 0, stream>>>(cp, xb, pos, tab);

  // 2. QKV projections with fused RoPE/repack/V-transpose epilogue
  QKVArgs qp;
  qp.A[0] = wqb; qp.A[1] = wkb; qp.A[2] = xb;
  qp.B[0] = xb;  qp.B[1] = xb;  qp.B[2] = wvb;
  qp.dst[0] = Qbf; qp.dst[1] = Kbf; qp.dst[2] = Vtb;
  qp.tab = tab;
  gemm_qkv_fused<<<dim3(256, 1, 3), 256, 0, stream>>>(qp);

  // 3. flash attention: 1024 8-wave key-split blocks (32 waves/CU)
  attn_mfma<<<dim3(1024), 512, 0, stream>>>(Qbf, Kbf, Vtb, obb);

  // 4. output projection (128x64 tiles, 512 blocks)
  gemm_out_bf16<<<dim3(D_MODEL / 64, MROWS / 128), 256, 0, stream>>>(obb, wob, (float*)d_out);
}